// Round 2
// baseline (1141.370 us; speedup 1.0000x reference)
//
#include <hip/hip_runtime.h>

#define AS1 __attribute__((address_space(1)))
#define AS3 __attribute__((address_space(3)))

typedef __attribute__((ext_vector_type(8))) short short8;
typedef __attribute__((ext_vector_type(4))) float f32x4;

static __device__ __forceinline__ unsigned short f2bf(float f) {
    unsigned u = __builtin_bit_cast(unsigned, f);
    u += 0x7FFFu + ((u >> 16) & 1u);
    return (unsigned short)(u >> 16);
}

// ---------------- conversion kernels ----------------

__global__ void cvt_bf16_kernel(const float* __restrict__ in,
                                unsigned short* __restrict__ out, int n8) {
    int i = blockIdx.x * blockDim.x + threadIdx.x;
    int stride = gridDim.x * blockDim.x;
    for (; i < n8; i += stride) {
        const float4* p = (const float4*)in + 2 * (size_t)i;
        float4 a = p[0], b = p[1];
        short8 o;
        o[0] = f2bf(a.x); o[1] = f2bf(a.y); o[2] = f2bf(a.z); o[3] = f2bf(a.w);
        o[4] = f2bf(b.x); o[5] = f2bf(b.y); o[6] = f2bf(b.z); o[7] = f2bf(b.w);
        *(short8*)(out + 8 * (size_t)i) = o;
    }
}

// out[m,k] = bf16(wa[m,k] * wb[k]),  K = 512 fixed
__global__ void wab_kernel(const float* __restrict__ wa, const float* __restrict__ wb,
                           unsigned short* __restrict__ out, int n8) {
    int i = blockIdx.x * blockDim.x + threadIdx.x;
    int stride = gridDim.x * blockDim.x;
    for (; i < n8; i += stride) {
        int base = i * 8;
        int k = base & 511;
        const float4* pa = (const float4*)(wa + base);
        const float4* pb = (const float4*)(wb + k);
        float4 a0 = pa[0], a1 = pa[1], b0 = pb[0], b1 = pb[1];
        short8 o;
        o[0] = f2bf(a0.x * b0.x); o[1] = f2bf(a0.y * b0.y);
        o[2] = f2bf(a0.z * b0.z); o[3] = f2bf(a0.w * b0.w);
        o[4] = f2bf(a1.x * b1.x); o[5] = f2bf(a1.y * b1.y);
        o[6] = f2bf(a1.z * b1.z); o[7] = f2bf(a1.w * b1.w);
        *(short8*)(out + 8 * (size_t)i) = o;
    }
}

// wc[512][N] -> out[N][512] bf16 (transpose)
__global__ void wcT_kernel(const float* __restrict__ wc,
                           unsigned short* __restrict__ out, int N) {
    int i = blockIdx.x * blockDim.x + threadIdx.x;
    int total = N * 512;
    int stride = gridDim.x * blockDim.x;
    for (; i < total; i += stride) {
        int n = i >> 9, k = i & 511;
        out[i] = f2bf(wc[(size_t)k * N + n]);
    }
}

__global__ void bih_kernel(const float* __restrict__ b1, const float* __restrict__ ib1,
                           float* __restrict__ out) {
    int i = blockIdx.x * blockDim.x + threadIdx.x;
    if (i < 1536) out[i] = (i < 1024) ? b1[i] : ib1[i - 1024];
}

__global__ void scan_init_kernel(unsigned short* __restrict__ hbf,
                                 unsigned* __restrict__ bar) {
    int i = blockIdx.x * blockDim.x + threadIdx.x;
    if (i < 65536) hbf[i] = 0;
    if (i < 64) bar[i] = 0;
}

// ---------------- NT GEMM: C[M,N] = A[M,K](bf16) * B[N,K]^T(bf16) (+bias) ----------------
// 128x128 tile, BK=64, 256 threads (2x2 waves of 64x64), 16x16x32 bf16 MFMA, fp32 accum.

template <typename OutT, bool BIAS>
__global__ __launch_bounds__(256) void gemm_nt_kernel(
    const unsigned short* __restrict__ A, const unsigned short* __restrict__ B,
    OutT* __restrict__ C, const float* __restrict__ bias, int K, int ldC) {
    __shared__ __align__(16) unsigned short As[128 * 64];
    __shared__ __align__(16) unsigned short Bs[128 * 64];
    const int tid = threadIdx.x;
    const int wave = tid >> 6, lane = tid & 63;
    const long bm = (long)blockIdx.x * 128, bn = (long)blockIdx.y * 128;
    const int wr = (wave >> 1) * 64, wc = (wave & 1) * 64;
    f32x4 acc[4][4] = {};

    const int srow = tid >> 3;          // staging row within 32-row chunk
    const int scol = (tid & 7) * 8;     // staging col (bf16 elements)
    const unsigned short* Ag = A + bm * K + scol;
    const unsigned short* Bg = B + bn * K + scol;

    for (int kt = 0; kt < K; kt += 64) {
        __syncthreads();
#pragma unroll
        for (int i = 0; i < 4; ++i) {
            __builtin_amdgcn_global_load_lds(
                (const AS1 void*)(Ag + (long)(i * 32 + srow) * K + kt),
                (AS3 void*)(As + i * 2048 + wave * 512), 16, 0, 0);
        }
#pragma unroll
        for (int i = 0; i < 4; ++i) {
            __builtin_amdgcn_global_load_lds(
                (const AS1 void*)(Bg + (long)(i * 32 + srow) * K + kt),
                (AS3 void*)(Bs + i * 2048 + wave * 512), 16, 0, 0);
        }
        __syncthreads();
#pragma unroll
        for (int kk = 0; kk < 2; ++kk) {
            const int ko = kk * 32 + (lane >> 4) * 8;
            short8 af[4], bfr[4];
#pragma unroll
            for (int mi = 0; mi < 4; ++mi)
                af[mi] = *(const short8*)(As + (wr + mi * 16 + (lane & 15)) * 64 + ko);
#pragma unroll
            for (int ni = 0; ni < 4; ++ni)
                bfr[ni] = *(const short8*)(Bs + (wc + ni * 16 + (lane & 15)) * 64 + ko);
#pragma unroll
            for (int mi = 0; mi < 4; ++mi)
#pragma unroll
                for (int ni = 0; ni < 4; ++ni)
                    acc[mi][ni] = __builtin_amdgcn_mfma_f32_16x16x32_bf16(
                        af[mi], bfr[ni], acc[mi][ni], 0, 0, 0);
        }
    }

    const int rbase = (lane >> 4) * 4;
    const int cbase = lane & 15;
#pragma unroll
    for (int mi = 0; mi < 4; ++mi) {
#pragma unroll
        for (int ni = 0; ni < 4; ++ni) {
            long gc = bn + wc + ni * 16 + cbase;
            float bv = BIAS ? bias[gc] : 0.f;
#pragma unroll
            for (int j = 0; j < 4; ++j) {
                long gr = bm + wr + mi * 16 + rbase + j;
                float v = acc[mi][ni][j] + bv;
                if constexpr (sizeof(OutT) == 2)
                    C[gr * ldC + gc] = (OutT)f2bf(v);
                else
                    C[gr * ldC + gc] = v;
            }
        }
    }
}

// ---------------- persistent GRU scan kernel ----------------
// 64 blocks x 256 threads = 256 waves; wave w owns batch rows [ (w>>5)*16, +16 )
// and h-cols [ (w&31)*16, +16 ). whh fragments for all 3 gates stay in registers
// (48 x short8 = 192 VGPRs). h ping-pongs in a global bf16 buffer; hand-rolled
// device-scope grid barrier between steps (one counter per step, pre-zeroed).

__global__ __launch_bounds__(256, 1) void gru_scan_kernel(
    unsigned short* __restrict__ hbuf,        // 2 x [128][512] bf16 ping-pong
    const unsigned short* __restrict__ whh,   // [1536][512] bf16
    const float* __restrict__ bhh,
    const float* __restrict__ gi, const float* __restrict__ gf,
    float* __restrict__ out, float* __restrict__ hT,
    unsigned* __restrict__ bar) {
    const int tid = threadIdx.x;
    const int lane = tid & 63;
    const int w = blockIdx.x * 4 + (tid >> 6);   // 0..255
    const int r0 = (w >> 5) * 16;                // batch rowgroup
    const int c0 = (w & 31) * 16;                // h colgroup
    const int lrow = lane & 15;
    const int lko = (lane >> 4) * 8;

    // Resident whh B-fragments: wf[g][kk] covers cols [c0,c0+16), k [kk*32,+32)
    short8 wf[3][16];
#pragma unroll
    for (int g = 0; g < 3; ++g)
#pragma unroll
        for (int kk = 0; kk < 16; ++kk)
            wf[g][kk] = *(const short8*)(whh + (size_t)(g * 512 + c0 + lrow) * 512 + kk * 32 + lko);

    const int hc = c0 + lrow;
    const float br = bhh[hc], bz = bhh[512 + hc], bn_ = bhh[1024 + hc];
    float hprev[4] = {0.f, 0.f, 0.f, 0.f};
    const int rb = r0 + (lane >> 4) * 4;

    for (int t = 0; t < 64; ++t) {
        const int p = t & 1;
        const unsigned short* hin = hbuf + p * 65536;
        unsigned short* hout = hbuf + (p ^ 1) * 65536;

        f32x4 acc0 = {}, acc1 = {}, acc2 = {};
        const unsigned short* ha = hin + (size_t)(r0 + lrow) * 512 + lko;
#pragma unroll
        for (int kk = 0; kk < 16; ++kk) {
            short8 a = *(const short8*)(ha + kk * 32);
            acc0 = __builtin_amdgcn_mfma_f32_16x16x32_bf16(a, wf[0][kk], acc0, 0, 0, 0);
            acc1 = __builtin_amdgcn_mfma_f32_16x16x32_bf16(a, wf[1][kk], acc1, 0, 0, 0);
            acc2 = __builtin_amdgcn_mfma_f32_16x16x32_bf16(a, wf[2][kk], acc2, 0, 0, 0);
        }

#pragma unroll
        for (int j = 0; j < 4; ++j) {
            const int bb = rb + j;
            const size_t grow = (size_t)bb * 64 + t;
            float ir  = gi[grow * 1536 + hc];
            float ii  = gi[grow * 1536 + 512 + hc];
            float inn = gi[grow * 1536 + 1024 + hc];
            float fr  = gf[grow * 1024 + hc];
            float fi  = gf[grow * 1024 + 512 + hc];
            float r = 1.f / (1.f + __expf(-(ir + acc0[j] + br + fr)));
            float z = 1.f / (1.f + __expf(-(ii + acc1[j] + bz + fi)));
            float n = tanhf(inn + r * (acc2[j] + bn_));
            float hy = n + z * (hprev[j] - n);
            hprev[j] = hy;
            hout[(size_t)bb * 512 + hc] = f2bf(hy);
            out[((size_t)bb * 64 + t) * 512 + hc] = hy;
            if (t == 63) hT[(size_t)bb * 512 + hc] = hy;
        }

        if (t < 63) {
            // device-scope grid barrier: release stores, arrive, spin, acquire
            __threadfence();
            __syncthreads();
            if (tid == 0) {
                __hip_atomic_fetch_add(&bar[t], 1u, __ATOMIC_RELAXED,
                                       __HIP_MEMORY_SCOPE_AGENT);
                while (__hip_atomic_load(&bar[t], __ATOMIC_RELAXED,
                                         __HIP_MEMORY_SCOPE_AGENT) < 64u)
                    __builtin_amdgcn_s_sleep(2);
                __threadfence();
            }
            __syncthreads();
        }
    }
}

// ---------------- host launcher ----------------

extern "C" void kernel_launch(void* const* d_in, const int* in_sizes, int n_in,
                              void* d_out, int out_size, void* d_ws, size_t ws_size,
                              hipStream_t stream) {
    (void)in_sizes; (void)n_in; (void)out_size; (void)ws_size;

    const float* x0  = (const float*)d_in[0];
    const float* x1  = (const float*)d_in[1];
    const float* wa0 = (const float*)d_in[2];
    const float* wb0 = (const float*)d_in[3];
    const float* wc0 = (const float*)d_in[4];
    const float* b0  = (const float*)d_in[5];
    const float* wa1 = (const float*)d_in[6];
    const float* wb1 = (const float*)d_in[7];
    const float* wc1 = (const float*)d_in[8];
    const float* b1  = (const float*)d_in[9];
    const float* iw1 = (const float*)d_in[10];
    const float* ib1 = (const float*)d_in[11];
    const float* whh = (const float*)d_in[12];
    const float* bhh = (const float*)d_in[13];

    float* out = (float*)d_out;                  // [128,64,512]
    float* hT  = out + (size_t)128 * 64 * 512;   // [128,512]

    char* w = (char*)d_ws;
    auto alloc = [&](size_t bytes) {
        char* p = w;
        w += (bytes + 255) & ~(size_t)255;
        return p;
    };
    unsigned short* x1bf = (unsigned short*)alloc((size_t)8192 * 2048 * 2);
    unsigned short* x0bf = (unsigned short*)alloc((size_t)8192 * 1536 * 2);
    unsigned short* wih  = (unsigned short*)alloc((size_t)1536 * 2048 * 2);
    unsigned short* wfh  = (unsigned short*)alloc((size_t)1024 * 1536 * 2);
    unsigned short* wab0 = (unsigned short*)alloc((size_t)1024 * 512 * 2);
    unsigned short* wab1 = (unsigned short*)alloc((size_t)1024 * 512 * 2);
    unsigned short* wc0T = (unsigned short*)alloc((size_t)1536 * 512 * 2);
    unsigned short* wc1T = (unsigned short*)alloc((size_t)2048 * 512 * 2);
    unsigned short* whhb = (unsigned short*)alloc((size_t)1536 * 512 * 2);
    float* bih = (float*)alloc(1536 * 4);
    unsigned short* hbf = (unsigned short*)alloc((size_t)2 * 65536 * 2);
    unsigned* bar = (unsigned*)alloc(64 * 4);
    float* gi  = (float*)alloc((size_t)8192 * 1536 * 4);
    float* gf  = (float*)alloc((size_t)8192 * 1024 * 4);

    // conversions
    cvt_bf16_kernel<<<2048, 256, 0, stream>>>(x1, x1bf, (8192 * 2048) / 8);
    cvt_bf16_kernel<<<2048, 256, 0, stream>>>(x0, x0bf, (8192 * 1536) / 8);
    wab_kernel<<<256, 256, 0, stream>>>(wa0, wb0, wab0, (1024 * 512) / 8);
    wab_kernel<<<256, 256, 0, stream>>>(wa1, wb1, wab1, (1024 * 512) / 8);
    wcT_kernel<<<768, 256, 0, stream>>>(wc0, wc0T, 1536);
    wcT_kernel<<<1024, 256, 0, stream>>>(wc1, wc1T, 2048);
    cvt_bf16_kernel<<<384, 256, 0, stream>>>(whh, whhb, (1536 * 512) / 8);
    cvt_bf16_kernel<<<512, 256, 0, stream>>>(iw1, wih + (size_t)1024 * 2048, (512 * 2048) / 8);
    bih_kernel<<<6, 256, 0, stream>>>(b1, ib1, bih);
    scan_init_kernel<<<256, 256, 0, stream>>>(hbf, bar);

    // weight GEMMs: w_fh[1024,1536], w_ih[0:1024,2048]
    gemm_nt_kernel<unsigned short, false><<<dim3(8, 12), 256, 0, stream>>>(
        wab0, wc0T, wfh, nullptr, 512, 1536);
    gemm_nt_kernel<unsigned short, false><<<dim3(8, 16), 256, 0, stream>>>(
        wab1, wc1T, wih, nullptr, 512, 2048);

    // big projections: gi[8192,1536], gf[8192,1024]
    gemm_nt_kernel<float, true><<<dim3(64, 12), 256, 0, stream>>>(
        x1bf, wih, gi, bih, 2048, 1536);
    gemm_nt_kernel<float, true><<<dim3(64, 8), 256, 0, stream>>>(
        x0bf, wfh, gf, b0, 1536, 1024);

    // persistent scan: 64 blocks (<=256 CUs, 1 block/CU -> all co-resident)
    gru_scan_kernel<<<64, 256, 0, stream>>>(hbf, whhb, bhh, gi, gf, out, hT, bar);
}

// Round 3
// 711.356 us; speedup vs baseline: 1.6045x; 1.6045x over previous
//
#include <hip/hip_runtime.h>

#define AS1 __attribute__((address_space(1)))
#define AS3 __attribute__((address_space(3)))

typedef __attribute__((ext_vector_type(8))) short short8;
typedef __attribute__((ext_vector_type(4))) float f32x4;

static __device__ __forceinline__ unsigned short f2bf(float f) {
    unsigned u = __builtin_bit_cast(unsigned, f);
    u += 0x7FFFu + ((u >> 16) & 1u);
    return (unsigned short)(u >> 16);
}

// ---------------- conversion kernels ----------------

__global__ void cvt_bf16_kernel(const float* __restrict__ in,
                                unsigned short* __restrict__ out, int n8) {
    int i = blockIdx.x * blockDim.x + threadIdx.x;
    int stride = gridDim.x * blockDim.x;
    for (; i < n8; i += stride) {
        const float4* p = (const float4*)in + 2 * (size_t)i;
        float4 a = p[0], b = p[1];
        short8 o;
        o[0] = f2bf(a.x); o[1] = f2bf(a.y); o[2] = f2bf(a.z); o[3] = f2bf(a.w);
        o[4] = f2bf(b.x); o[5] = f2bf(b.y); o[6] = f2bf(b.z); o[7] = f2bf(b.w);
        *(short8*)(out + 8 * (size_t)i) = o;
    }
}

// out[m,k] = bf16(wa[m,k] * wb[k]),  K = 512 fixed
__global__ void wab_kernel(const float* __restrict__ wa, const float* __restrict__ wb,
                           unsigned short* __restrict__ out, int n8) {
    int i = blockIdx.x * blockDim.x + threadIdx.x;
    int stride = gridDim.x * blockDim.x;
    for (; i < n8; i += stride) {
        int base = i * 8;
        int k = base & 511;
        const float4* pa = (const float4*)(wa + base);
        const float4* pb = (const float4*)(wb + k);
        float4 a0 = pa[0], a1 = pa[1], b0 = pb[0], b1 = pb[1];
        short8 o;
        o[0] = f2bf(a0.x * b0.x); o[1] = f2bf(a0.y * b0.y);
        o[2] = f2bf(a0.z * b0.z); o[3] = f2bf(a0.w * b0.w);
        o[4] = f2bf(a1.x * b1.x); o[5] = f2bf(a1.y * b1.y);
        o[6] = f2bf(a1.z * b1.z); o[7] = f2bf(a1.w * b1.w);
        *(short8*)(out + 8 * (size_t)i) = o;
    }
}

// wc[512][N] -> out[N][512] bf16 (transpose)
__global__ void wcT_kernel(const float* __restrict__ wc,
                           unsigned short* __restrict__ out, int N) {
    int i = blockIdx.x * blockDim.x + threadIdx.x;
    int total = N * 512;
    int stride = gridDim.x * blockDim.x;
    for (; i < total; i += stride) {
        int n = i >> 9, k = i & 511;
        out[i] = f2bf(wc[(size_t)k * N + n]);
    }
}

__global__ void bih_kernel(const float* __restrict__ b1, const float* __restrict__ ib1,
                           float* __restrict__ out) {
    int i = blockIdx.x * blockDim.x + threadIdx.x;
    if (i < 1536) out[i] = (i < 1024) ? b1[i] : ib1[i - 1024];
}

__global__ void scan_init_kernel(unsigned short* __restrict__ hbf,
                                 unsigned* __restrict__ bar) {
    int i = blockIdx.x * blockDim.x + threadIdx.x;
    if (i < 65536) hbf[i] = 0;
    if (i < 64) bar[i] = 0;
}

// ---------------- NT GEMM: C[M,N] = A[M,K](bf16) * B[N,K]^T(bf16) (+bias) ----------------
// 128x128 tile, BK=64, 256 threads (2x2 waves of 64x64), 16x16x32 bf16 MFMA, fp32 accum.

template <typename OutT, bool BIAS>
__global__ __launch_bounds__(256) void gemm_nt_kernel(
    const unsigned short* __restrict__ A, const unsigned short* __restrict__ B,
    OutT* __restrict__ C, const float* __restrict__ bias, int K, int ldC) {
    __shared__ __align__(16) unsigned short As[128 * 64];
    __shared__ __align__(16) unsigned short Bs[128 * 64];
    const int tid = threadIdx.x;
    const int wave = tid >> 6, lane = tid & 63;
    const long bm = (long)blockIdx.x * 128, bn = (long)blockIdx.y * 128;
    const int wr = (wave >> 1) * 64, wc = (wave & 1) * 64;
    f32x4 acc[4][4] = {};

    const int srow = tid >> 3;          // staging row within 32-row chunk
    const int scol = (tid & 7) * 8;     // staging col (bf16 elements)
    const unsigned short* Ag = A + bm * K + scol;
    const unsigned short* Bg = B + bn * K + scol;

    for (int kt = 0; kt < K; kt += 64) {
        __syncthreads();
#pragma unroll
        for (int i = 0; i < 4; ++i) {
            __builtin_amdgcn_global_load_lds(
                (const AS1 void*)(Ag + (long)(i * 32 + srow) * K + kt),
                (AS3 void*)(As + i * 2048 + wave * 512), 16, 0, 0);
        }
#pragma unroll
        for (int i = 0; i < 4; ++i) {
            __builtin_amdgcn_global_load_lds(
                (const AS1 void*)(Bg + (long)(i * 32 + srow) * K + kt),
                (AS3 void*)(Bs + i * 2048 + wave * 512), 16, 0, 0);
        }
        __syncthreads();
#pragma unroll
        for (int kk = 0; kk < 2; ++kk) {
            const int ko = kk * 32 + (lane >> 4) * 8;
            short8 af[4], bfr[4];
#pragma unroll
            for (int mi = 0; mi < 4; ++mi)
                af[mi] = *(const short8*)(As + (wr + mi * 16 + (lane & 15)) * 64 + ko);
#pragma unroll
            for (int ni = 0; ni < 4; ++ni)
                bfr[ni] = *(const short8*)(Bs + (wc + ni * 16 + (lane & 15)) * 64 + ko);
#pragma unroll
            for (int mi = 0; mi < 4; ++mi)
#pragma unroll
                for (int ni = 0; ni < 4; ++ni)
                    acc[mi][ni] = __builtin_amdgcn_mfma_f32_16x16x32_bf16(
                        af[mi], bfr[ni], acc[mi][ni], 0, 0, 0);
        }
    }

    const int rbase = (lane >> 4) * 4;
    const int cbase = lane & 15;
#pragma unroll
    for (int mi = 0; mi < 4; ++mi) {
#pragma unroll
        for (int ni = 0; ni < 4; ++ni) {
            long gc = bn + wc + ni * 16 + cbase;
            float bv = BIAS ? bias[gc] : 0.f;
#pragma unroll
            for (int j = 0; j < 4; ++j) {
                long gr = bm + wr + mi * 16 + rbase + j;
                float v = acc[mi][ni][j] + bv;
                if constexpr (sizeof(OutT) == 2)
                    C[gr * ldC + gc] = (OutT)f2bf(v);
                else
                    C[gr * ldC + gc] = v;
            }
        }
    }
}

// ---------------- persistent GRU scan kernel (selective-coherence barrier) ----------------
// 64 blocks x 256 threads = 256 waves; wave w owns batch rows [(w>>5)*16,+16) and
// h-cols [(w&31)*16,+16). whh fragments register-resident. h ping-pongs through
// agent-scope (sc1, L2-bypassing) atomic stores/loads -- the ONLY cross-XCD traffic.
// No __threadfence (no L2 writeback/invalidate). Grid barrier: __syncthreads drains
// each block's h-stores (vmcnt0), leader does relaxed agent atomic arrive+spin,
// gi/gf prefetch for t+1 issued by all threads under the spin.

__global__ __launch_bounds__(256, 1) void gru_scan_kernel(
    unsigned short* __restrict__ hbuf,        // 2 x [128][512] bf16 ping-pong
    const unsigned short* __restrict__ whh,   // [1536][512] bf16
    const float* __restrict__ bhh,
    const float* __restrict__ gi, const float* __restrict__ gf,
    float* __restrict__ out, float* __restrict__ hT,
    unsigned* __restrict__ bar) {
    const int tid = threadIdx.x;
    const int lane = tid & 63;
    const int w = blockIdx.x * 4 + (tid >> 6);   // 0..255
    const int r0 = (w >> 5) * 16;                // batch rowgroup
    const int c0 = (w & 31) * 16;                // h colgroup
    const int lrow = lane & 15;
    const int lko = (lane >> 4) * 8;

    // Resident whh B-fragments: wf[g][kk] covers cols [c0,c0+16), k [kk*32,+32)
    short8 wf[3][16];
#pragma unroll
    for (int g = 0; g < 3; ++g)
#pragma unroll
        for (int kk = 0; kk < 16; ++kk)
            wf[g][kk] = *(const short8*)(whh + (size_t)(g * 512 + c0 + lrow) * 512 + kk * 32 + lko);

    const int hc = c0 + lrow;
    const float br = bhh[hc], bz = bhh[512 + hc], bn_ = bhh[1024 + hc];
    const int rb = r0 + (lane >> 4) * 4;

    float hprev[4] = {0.f, 0.f, 0.f, 0.f};
    float pir[4], pii[4], pinn[4], pfr[4], pfi[4];

    auto PF = [&](int t) {
#pragma unroll
        for (int j = 0; j < 4; ++j) {
            size_t grow = (size_t)(rb + j) * 64 + t;
            pir[j]  = gi[grow * 1536 + hc];
            pii[j]  = gi[grow * 1536 + 512 + hc];
            pinn[j] = gi[grow * 1536 + 1024 + hc];
            pfr[j]  = gf[grow * 1024 + hc];
            pfi[j]  = gf[grow * 1024 + 512 + hc];
        }
    };
    PF(0);

    for (int t = 0; t < 64; ++t) {
        const int p = t & 1;
        const unsigned short* hin = hbuf + p * 65536;
        unsigned short* hout = hbuf + (p ^ 1) * 65536;

        f32x4 acc0 = {}, acc1 = {}, acc2 = {};
        const unsigned long long* ha =
            (const unsigned long long*)(hin + (size_t)(r0 + lrow) * 512 + lko);
#pragma unroll
        for (int kk = 0; kk < 16; ++kk) {
            // 16B fragment = two 8B agent-scope loads (sc1: bypass stale L2/L1)
            unsigned long long q0 = __hip_atomic_load(ha + kk * 8, __ATOMIC_RELAXED,
                                                      __HIP_MEMORY_SCOPE_AGENT);
            unsigned long long q1 = __hip_atomic_load(ha + kk * 8 + 1, __ATOMIC_RELAXED,
                                                      __HIP_MEMORY_SCOPE_AGENT);
            union { unsigned long long q[2]; short8 v; } u;
            u.q[0] = q0; u.q[1] = q1;
            short8 a = u.v;
            acc0 = __builtin_amdgcn_mfma_f32_16x16x32_bf16(a, wf[0][kk], acc0, 0, 0, 0);
            acc1 = __builtin_amdgcn_mfma_f32_16x16x32_bf16(a, wf[1][kk], acc1, 0, 0, 0);
            acc2 = __builtin_amdgcn_mfma_f32_16x16x32_bf16(a, wf[2][kk], acc2, 0, 0, 0);
        }

        float hy4[4];
#pragma unroll
        for (int j = 0; j < 4; ++j) {
            float r = 1.f / (1.f + __expf(-(pir[j] + acc0[j] + br + pfr[j])));
            float z = 1.f / (1.f + __expf(-(pii[j] + acc1[j] + bz + pfi[j])));
            float n = tanhf(pinn[j] + r * (acc2[j] + bn_));
            float hy = n + z * (hprev[j] - n);
            hprev[j] = hy;
            hy4[j] = hy;
            __builtin_nontemporal_store(hy, &out[((size_t)(rb + j) * 64 + t) * 512 + hc]);
        }
#pragma unroll
        for (int j = 0; j < 4; ++j)
            __hip_atomic_store(hout + (size_t)(rb + j) * 512 + hc,
                               (unsigned short)f2bf(hy4[j]),
                               __ATOMIC_RELAXED, __HIP_MEMORY_SCOPE_AGENT);

        if (t == 63) {
#pragma unroll
            for (int j = 0; j < 4; ++j)
                __builtin_nontemporal_store(hy4[j], &hT[(size_t)(rb + j) * 512 + hc]);
        } else {
            // __syncthreads drains vmcnt(0): all 4 waves' sc1 h-stores are ack'd at
            // the coherence point before the leader arrives.
            __syncthreads();
            if (tid == 0)
                __hip_atomic_fetch_add(&bar[t], 1u, __ATOMIC_RELAXED,
                                       __HIP_MEMORY_SCOPE_AGENT);
            PF(t + 1);   // prefetch next step's gi/gf; latency hides under the spin
            if (tid == 0) {
                while (__hip_atomic_load(&bar[t], __ATOMIC_RELAXED,
                                         __HIP_MEMORY_SCOPE_AGENT) < 64u)
                    __builtin_amdgcn_s_sleep(1);
            }
            __syncthreads();
        }
    }
}

// ---------------- host launcher ----------------

extern "C" void kernel_launch(void* const* d_in, const int* in_sizes, int n_in,
                              void* d_out, int out_size, void* d_ws, size_t ws_size,
                              hipStream_t stream) {
    (void)in_sizes; (void)n_in; (void)out_size; (void)ws_size;

    const float* x0  = (const float*)d_in[0];
    const float* x1  = (const float*)d_in[1];
    const float* wa0 = (const float*)d_in[2];
    const float* wb0 = (const float*)d_in[3];
    const float* wc0 = (const float*)d_in[4];
    const float* b0  = (const float*)d_in[5];
    const float* wa1 = (const float*)d_in[6];
    const float* wb1 = (const float*)d_in[7];
    const float* wc1 = (const float*)d_in[8];
    const float* b1  = (const float*)d_in[9];
    const float* iw1 = (const float*)d_in[10];
    const float* ib1 = (const float*)d_in[11];
    const float* whh = (const float*)d_in[12];
    const float* bhh = (const float*)d_in[13];

    float* out = (float*)d_out;                  // [128,64,512]
    float* hT  = out + (size_t)128 * 64 * 512;   // [128,512]

    char* w = (char*)d_ws;
    auto alloc = [&](size_t bytes) {
        char* p = w;
        w += (bytes + 255) & ~(size_t)255;
        return p;
    };
    unsigned short* x1bf = (unsigned short*)alloc((size_t)8192 * 2048 * 2);
    unsigned short* x0bf = (unsigned short*)alloc((size_t)8192 * 1536 * 2);
    unsigned short* wih  = (unsigned short*)alloc((size_t)1536 * 2048 * 2);
    unsigned short* wfh  = (unsigned short*)alloc((size_t)1024 * 1536 * 2);
    unsigned short* wab0 = (unsigned short*)alloc((size_t)1024 * 512 * 2);
    unsigned short* wab1 = (unsigned short*)alloc((size_t)1024 * 512 * 2);
    unsigned short* wc0T = (unsigned short*)alloc((size_t)1536 * 512 * 2);
    unsigned short* wc1T = (unsigned short*)alloc((size_t)2048 * 512 * 2);
    unsigned short* whhb = (unsigned short*)alloc((size_t)1536 * 512 * 2);
    float* bih = (float*)alloc(1536 * 4);
    unsigned short* hbf = (unsigned short*)alloc((size_t)2 * 65536 * 2);
    unsigned* bar = (unsigned*)alloc(64 * 4);
    float* gi  = (float*)alloc((size_t)8192 * 1536 * 4);
    float* gf  = (float*)alloc((size_t)8192 * 1024 * 4);

    // conversions
    cvt_bf16_kernel<<<2048, 256, 0, stream>>>(x1, x1bf, (8192 * 2048) / 8);
    cvt_bf16_kernel<<<2048, 256, 0, stream>>>(x0, x0bf, (8192 * 1536) / 8);
    wab_kernel<<<256, 256, 0, stream>>>(wa0, wb0, wab0, (1024 * 512) / 8);
    wab_kernel<<<256, 256, 0, stream>>>(wa1, wb1, wab1, (1024 * 512) / 8);
    wcT_kernel<<<768, 256, 0, stream>>>(wc0, wc0T, 1536);
    wcT_kernel<<<1024, 256, 0, stream>>>(wc1, wc1T, 2048);
    cvt_bf16_kernel<<<384, 256, 0, stream>>>(whh, whhb, (1536 * 512) / 8);
    cvt_bf16_kernel<<<512, 256, 0, stream>>>(iw1, wih + (size_t)1024 * 2048, (512 * 2048) / 8);
    bih_kernel<<<6, 256, 0, stream>>>(b1, ib1, bih);
    scan_init_kernel<<<256, 256, 0, stream>>>(hbf, bar);

    // weight GEMMs: w_fh[1024,1536], w_ih[0:1024,2048]
    gemm_nt_kernel<unsigned short, false><<<dim3(8, 12), 256, 0, stream>>>(
        wab0, wc0T, wfh, nullptr, 512, 1536);
    gemm_nt_kernel<unsigned short, false><<<dim3(8, 16), 256, 0, stream>>>(
        wab1, wc1T, wih, nullptr, 512, 2048);

    // big projections: gi[8192,1536], gf[8192,1024]
    gemm_nt_kernel<float, true><<<dim3(64, 12), 256, 0, stream>>>(
        x1bf, wih, gi, bih, 2048, 1536);
    gemm_nt_kernel<float, true><<<dim3(64, 8), 256, 0, stream>>>(
        x0bf, wfh, gf, b0, 1536, 1024);

    // persistent scan: 64 blocks (1 block/CU, all co-resident)
    gru_scan_kernel<<<64, 256, 0, stream>>>(hbf, whhb, bhh, gi, gf, out, hT, bar);
}

// Round 5
// 632.005 us; speedup vs baseline: 1.8060x; 1.1256x over previous
//
#include <hip/hip_runtime.h>

#define AS1 __attribute__((address_space(1)))
#define AS3 __attribute__((address_space(3)))

typedef __attribute__((ext_vector_type(8))) short short8;
typedef __attribute__((ext_vector_type(4))) float f32x4;

static __device__ __forceinline__ unsigned short f2bf(float f) {
    unsigned u = __builtin_bit_cast(unsigned, f);
    u += 0x7FFFu + ((u >> 16) & 1u);
    return (unsigned short)(u >> 16);
}

// ---------------- conversion kernels ----------------

__global__ void cvt_bf16_kernel(const float* __restrict__ in,
                                unsigned short* __restrict__ out, int n8) {
    int i = blockIdx.x * blockDim.x + threadIdx.x;
    int stride = gridDim.x * blockDim.x;
    for (; i < n8; i += stride) {
        const float4* p = (const float4*)in + 2 * (size_t)i;
        float4 a = p[0], b = p[1];
        short8 o;
        o[0] = f2bf(a.x); o[1] = f2bf(a.y); o[2] = f2bf(a.z); o[3] = f2bf(a.w);
        o[4] = f2bf(b.x); o[5] = f2bf(b.y); o[6] = f2bf(b.z); o[7] = f2bf(b.w);
        *(short8*)(out + 8 * (size_t)i) = o;
    }
}

// out[m,k] = bf16(wa[m,k] * wb[k]),  K = 512 fixed
__global__ void wab_kernel(const float* __restrict__ wa, const float* __restrict__ wb,
                           unsigned short* __restrict__ out, int n8) {
    int i = blockIdx.x * blockDim.x + threadIdx.x;
    int stride = gridDim.x * blockDim.x;
    for (; i < n8; i += stride) {
        int base = i * 8;
        int k = base & 511;
        const float4* pa = (const float4*)(wa + base);
        const float4* pb = (const float4*)(wb + k);
        float4 a0 = pa[0], a1 = pa[1], b0 = pb[0], b1 = pb[1];
        short8 o;
        o[0] = f2bf(a0.x * b0.x); o[1] = f2bf(a0.y * b0.y);
        o[2] = f2bf(a0.z * b0.z); o[3] = f2bf(a0.w * b0.w);
        o[4] = f2bf(a1.x * b1.x); o[5] = f2bf(a1.y * b1.y);
        o[6] = f2bf(a1.z * b1.z); o[7] = f2bf(a1.w * b1.w);
        *(short8*)(out + 8 * (size_t)i) = o;
    }
}

// wc[512][N] -> out[N][512] bf16 (transpose)
__global__ void wcT_kernel(const float* __restrict__ wc,
                           unsigned short* __restrict__ out, int N) {
    int i = blockIdx.x * blockDim.x + threadIdx.x;
    int total = N * 512;
    int stride = gridDim.x * blockDim.x;
    for (; i < total; i += stride) {
        int n = i >> 9, k = i & 511;
        out[i] = f2bf(wc[(size_t)k * N + n]);
    }
}

__global__ void bih_kernel(const float* __restrict__ b1, const float* __restrict__ ib1,
                           float* __restrict__ out) {
    int i = blockIdx.x * blockDim.x + threadIdx.x;
    if (i < 1536) out[i] = (i < 1024) ? b1[i] : ib1[i - 1024];
}

__global__ void scan_init_kernel(unsigned short* __restrict__ hbf,
                                 unsigned* __restrict__ flags) {
    int i = blockIdx.x * blockDim.x + threadIdx.x;
    if (i < 65536) hbf[i] = 0;
    if (i < 128) flags[i] = 0;
}

// ---------------- NT GEMM: C[M,N] = A[M,K](bf16) * B[N,K]^T(bf16) (+bias) ----------------

template <typename OutT, bool BIAS>
__global__ __launch_bounds__(256) void gemm_nt_kernel(
    const unsigned short* __restrict__ A, const unsigned short* __restrict__ B,
    OutT* __restrict__ C, const float* __restrict__ bias, int K, int ldC) {
    __shared__ __align__(16) unsigned short As[128 * 64];
    __shared__ __align__(16) unsigned short Bs[128 * 64];
    const int tid = threadIdx.x;
    const int wave = tid >> 6, lane = tid & 63;
    const long bm = (long)blockIdx.x * 128, bn = (long)blockIdx.y * 128;
    const int wr = (wave >> 1) * 64, wc = (wave & 1) * 64;
    f32x4 acc[4][4] = {};

    const int srow = tid >> 3;
    const int scol = (tid & 7) * 8;
    const unsigned short* Ag = A + bm * K + scol;
    const unsigned short* Bg = B + bn * K + scol;

    for (int kt = 0; kt < K; kt += 64) {
        __syncthreads();
#pragma unroll
        for (int i = 0; i < 4; ++i) {
            __builtin_amdgcn_global_load_lds(
                (const AS1 void*)(Ag + (long)(i * 32 + srow) * K + kt),
                (AS3 void*)(As + i * 2048 + wave * 512), 16, 0, 0);
        }
#pragma unroll
        for (int i = 0; i < 4; ++i) {
            __builtin_amdgcn_global_load_lds(
                (const AS1 void*)(Bg + (long)(i * 32 + srow) * K + kt),
                (AS3 void*)(Bs + i * 2048 + wave * 512), 16, 0, 0);
        }
        __syncthreads();
#pragma unroll
        for (int kk = 0; kk < 2; ++kk) {
            const int ko = kk * 32 + (lane >> 4) * 8;
            short8 af[4], bfr[4];
#pragma unroll
            for (int mi = 0; mi < 4; ++mi)
                af[mi] = *(const short8*)(As + (wr + mi * 16 + (lane & 15)) * 64 + ko);
#pragma unroll
            for (int ni = 0; ni < 4; ++ni)
                bfr[ni] = *(const short8*)(Bs + (wc + ni * 16 + (lane & 15)) * 64 + ko);
#pragma unroll
            for (int mi = 0; mi < 4; ++mi)
#pragma unroll
                for (int ni = 0; ni < 4; ++ni)
                    acc[mi][ni] = __builtin_amdgcn_mfma_f32_16x16x32_bf16(
                        af[mi], bfr[ni], acc[mi][ni], 0, 0, 0);
        }
    }

    const int rbase = (lane >> 4) * 4;
    const int cbase = lane & 15;
#pragma unroll
    for (int mi = 0; mi < 4; ++mi) {
#pragma unroll
        for (int ni = 0; ni < 4; ++ni) {
            long gc = bn + wc + ni * 16 + cbase;
            float bv = BIAS ? bias[gc] : 0.f;
#pragma unroll
            for (int j = 0; j < 4; ++j) {
                long gr = bm + wr + mi * 16 + rbase + j;
                float v = acc[mi][ni][j] + bv;
                if constexpr (sizeof(OutT) == 2)
                    C[gr * ldC + gc] = (OutT)f2bf(v);
                else
                    C[gr * ldC + gc] = v;
            }
        }
    }
}

// ---------------- persistent GRU scan v4: team barriers + proper agent fences ----------------
// 64 blocks x 256 threads. Team = 8 blocks sharing batch-row strip [team*16,+16).
// Block (team,member) produces h cols [member*64,+64), consumes all 512.
// Handshake = cooperative-groups pattern: syncthreads (drain all waves' stores)
// -> tid0: agent RELEASE fence + relaxed flag store; waiter wave: relaxed spin
// -> one agent ACQUIRE fence -> syncthreads. All mutable cross-block data
// (h, flags, out, hT) stored write-through agent-scope so the release wbl2 has
// ~no dirty L2 lines to flush.

__global__ __launch_bounds__(256, 1) void gru_scan_kernel(
    unsigned short* __restrict__ hbuf,        // 2 x [128][512] bf16 ping-pong
    const unsigned short* __restrict__ whh,   // [1536][512] bf16
    const float* __restrict__ bhh,
    const float* __restrict__ gi, const float* __restrict__ gf,
    float* __restrict__ out, float* __restrict__ hT,
    unsigned* __restrict__ flags) {           // [8 teams][16] (64B/team)
    __shared__ __align__(16) unsigned short h_lds[16 * 512];  // 16KB, swizzled
    __shared__ __align__(16) float gis[48 * 68];              // [bbq*3+g][68]
    __shared__ __align__(16) float gfs[32 * 68];              // [bbq*2+g][68]

    const int tid = threadIdx.x;
    const int lane = tid & 63;
    const int wv = tid >> 6;
    const int team = blockIdx.x >> 3;
    const int member = blockIdx.x & 7;
    const int r0 = team * 16;
    const int cb = member * 64;
    const int c0 = cb + wv * 16;
    const int lrow = lane & 15;
    const int q = lane >> 4;

    // register-resident whh fragments: 3 gates x 16 K-frags, cols [c0,c0+16)
    short8 wf[3][16];
#pragma unroll
    for (int g = 0; g < 3; ++g)
#pragma unroll
        for (int kk = 0; kk < 16; ++kk)
            wf[g][kk] = *(const short8*)(whh + (size_t)(g * 512 + c0 + lrow) * 512 + kk * 32 + q * 8);

    const int hc = c0 + lrow;
    const float br = bhh[hc], bz = bhh[512 + hc], bn_ = bhh[1024 + hc];
    const int rb = r0 + q * 4;
    const int lc = wv * 16 + lrow;            // col within block's 64-col slab
    float hprev[4] = {0.f, 0.f, 0.f, 0.f};

    // slab prefetch: 5 x float4/thread; chunk = 256B of (row bbq, gate) slice
    const int chunk_sub = tid >> 4;           // 0..15
    const int u4 = (tid & 15) * 4;
    float4 sl[5];
    auto slab_load = [&](int t) {
#pragma unroll
        for (int k = 0; k < 5; ++k) {
            int chunk = k * 16 + chunk_sub;   // 0..79
            const float* p;
            if (chunk < 48) {
                int bbq = chunk / 3, g = chunk - bbq * 3;
                p = gi + ((size_t)(r0 + bbq) * 64 + t) * 1536 + g * 512 + cb + u4;
            } else {
                int c2 = chunk - 48, bbq = c2 >> 1, g2 = c2 & 1;
                p = gf + ((size_t)(r0 + bbq) * 64 + t) * 1024 + g2 * 512 + cb + u4;
            }
            sl[k] = *(const float4*)p;
        }
    };
    slab_load(0);

    for (int t = 0; t < 64; ++t) {
        // ---- wait for team's h(t) (skip at t=0; flags pre-zeroed = h(0) ready) ----
        if (t > 0 && tid < 64) {
            const unsigned tgt = (unsigned)t;
            for (;;) {
                unsigned v = __hip_atomic_load(&flags[team * 16 + (lane & 7)],
                                               __ATOMIC_RELAXED, __HIP_MEMORY_SCOPE_AGENT);
                if (__all((int)(v >= tgt))) break;
                __builtin_amdgcn_s_sleep(1);
            }
            // one acquire fence per waiting wave: inv L1 + XCD L2, orders spin->loads
            __builtin_amdgcn_fence(__ATOMIC_ACQUIRE, "agent");
        }
        __syncthreads();   // #1: everyone sees team-ready

        // ---- stage h(t) strip (16KB) into swizzled LDS: 8 x u64 agent loads ----
        {
            const unsigned short* hin = hbuf + (t & 1) * 65536;
            const int srow = tid >> 4;
            const unsigned long long* hs =
                (const unsigned long long*)(hin + (size_t)(r0 + srow) * 512);
            unsigned long long hq[8];
#pragma unroll
            for (int k = 0; k < 8; ++k)
                hq[k] = __hip_atomic_load(hs + (tid & 15) + k * 16,
                                          __ATOMIC_RELAXED, __HIP_MEMORY_SCOPE_AGENT);
            char* dst = (char*)h_lds + srow * 1024;
            const int sw = (srow & 7) << 4;
#pragma unroll
            for (int k = 0; k < 8; ++k) {
                int byte = ((tid & 15) + k * 16) * 8;
                *(unsigned long long*)(dst + (byte ^ sw)) = hq[k];
            }
        }
        // ---- redistribute slab(t) regs -> LDS ----
#pragma unroll
        for (int k = 0; k < 5; ++k) {
            int chunk = k * 16 + chunk_sub;
            float* d = (chunk < 48) ? &gis[chunk * 68] : &gfs[(chunk - 48) * 68];
            *(float4*)(d + u4) = sl[k];
        }
        __syncthreads();   // #2: LDS ready

        if (t < 63) slab_load(t + 1);   // latency hides under MFMA

        // ---- matvec: h(t) @ whh^T for 3 gates ----
        f32x4 acc0 = {}, acc1 = {}, acc2 = {};
        {
            const char* hl = (const char*)h_lds + lrow * 1024;
            const int sw2 = (lrow & 7) << 4;
#pragma unroll
            for (int kk = 0; kk < 16; ++kk) {
                short8 a = *(const short8*)(hl + ((kk * 64 + q * 16) ^ sw2));
                acc0 = __builtin_amdgcn_mfma_f32_16x16x32_bf16(a, wf[0][kk], acc0, 0, 0, 0);
                acc1 = __builtin_amdgcn_mfma_f32_16x16x32_bf16(a, wf[1][kk], acc1, 0, 0, 0);
                acc2 = __builtin_amdgcn_mfma_f32_16x16x32_bf16(a, wf[2][kk], acc2, 0, 0, 0);
            }
        }

        // ---- gates + h update (all stores write-through agent scope) ----
        float hy4[4];
        unsigned short* hout = hbuf + ((t & 1) ^ 1) * 65536;
#pragma unroll
        for (int j = 0; j < 4; ++j) {
            const int bbq = q * 4 + j;
            float ir  = gis[(bbq * 3 + 0) * 68 + lc];
            float ii  = gis[(bbq * 3 + 1) * 68 + lc];
            float inn = gis[(bbq * 3 + 2) * 68 + lc];
            float fr  = gfs[(bbq * 2 + 0) * 68 + lc];
            float fi  = gfs[(bbq * 2 + 1) * 68 + lc];
            float r = 1.f / (1.f + __expf(-(ir + acc0[j] + br + fr)));
            float z = 1.f / (1.f + __expf(-(ii + acc1[j] + bz + fi)));
            float n = tanhf(inn + r * (acc2[j] + bn_));
            float hy = n + z * (hprev[j] - n);
            hprev[j] = hy;
            hy4[j] = hy;
            __hip_atomic_store(hout + (size_t)(rb + j) * 512 + hc,
                               (unsigned short)f2bf(hy),
                               __ATOMIC_RELAXED, __HIP_MEMORY_SCOPE_AGENT);
            __hip_atomic_store(&out[((size_t)(rb + j) * 64 + t) * 512 + hc], hy,
                               __ATOMIC_RELAXED, __HIP_MEMORY_SCOPE_AGENT);
        }

        __syncthreads();   // #3: all waves' stores issued + vmcnt-drained
        if (t < 63) {
            if (tid == 0) {
                // release: make this block's h(t+1) stores agent-visible, then flag
                __builtin_amdgcn_fence(__ATOMIC_RELEASE, "agent");
                __hip_atomic_store(&flags[team * 16 + member], (unsigned)(t + 1),
                                   __ATOMIC_RELAXED, __HIP_MEMORY_SCOPE_AGENT);
            }
        } else {
#pragma unroll
            for (int j = 0; j < 4; ++j)
                __hip_atomic_store(&hT[(size_t)(rb + j) * 512 + hc], hy4[j],
                                   __ATOMIC_RELAXED, __HIP_MEMORY_SCOPE_AGENT);
        }
    }
}

// ---------------- host launcher ----------------

extern "C" void kernel_launch(void* const* d_in, const int* in_sizes, int n_in,
                              void* d_out, int out_size, void* d_ws, size_t ws_size,
                              hipStream_t stream) {
    (void)in_sizes; (void)n_in; (void)out_size; (void)ws_size;

    const float* x0  = (const float*)d_in[0];
    const float* x1  = (const float*)d_in[1];
    const float* wa0 = (const float*)d_in[2];
    const float* wb0 = (const float*)d_in[3];
    const float* wc0 = (const float*)d_in[4];
    const float* b0  = (const float*)d_in[5];
    const float* wa1 = (const float*)d_in[6];
    const float* wb1 = (const float*)d_in[7];
    const float* wc1 = (const float*)d_in[8];
    const float* b1  = (const float*)d_in[9];
    const float* iw1 = (const float*)d_in[10];
    const float* ib1 = (const float*)d_in[11];
    const float* whh = (const float*)d_in[12];
    const float* bhh = (const float*)d_in[13];

    float* out = (float*)d_out;                  // [128,64,512]
    float* hT  = out + (size_t)128 * 64 * 512;   // [128,512]

    char* w = (char*)d_ws;
    auto alloc = [&](size_t bytes) {
        char* p = w;
        w += (bytes + 255) & ~(size_t)255;
        return p;
    };
    unsigned short* x1bf = (unsigned short*)alloc((size_t)8192 * 2048 * 2);
    unsigned short* x0bf = (unsigned short*)alloc((size_t)8192 * 1536 * 2);
    unsigned short* wih  = (unsigned short*)alloc((size_t)1536 * 2048 * 2);
    unsigned short* wfh  = (unsigned short*)alloc((size_t)1024 * 1536 * 2);
    unsigned short* wab0 = (unsigned short*)alloc((size_t)1024 * 512 * 2);
    unsigned short* wab1 = (unsigned short*)alloc((size_t)1024 * 512 * 2);
    unsigned short* wc0T = (unsigned short*)alloc((size_t)1536 * 512 * 2);
    unsigned short* wc1T = (unsigned short*)alloc((size_t)2048 * 512 * 2);
    unsigned short* whhb = (unsigned short*)alloc((size_t)1536 * 512 * 2);
    float* bih = (float*)alloc(1536 * 4);
    unsigned short* hbf = (unsigned short*)alloc((size_t)2 * 65536 * 2);
    unsigned* flags = (unsigned*)alloc(128 * 4);
    float* gi  = (float*)alloc((size_t)8192 * 1536 * 4);
    float* gf  = (float*)alloc((size_t)8192 * 1024 * 4);

    // conversions
    cvt_bf16_kernel<<<2048, 256, 0, stream>>>(x1, x1bf, (8192 * 2048) / 8);
    cvt_bf16_kernel<<<2048, 256, 0, stream>>>(x0, x0bf, (8192 * 1536) / 8);
    wab_kernel<<<256, 256, 0, stream>>>(wa0, wb0, wab0, (1024 * 512) / 8);
    wab_kernel<<<256, 256, 0, stream>>>(wa1, wb1, wab1, (1024 * 512) / 8);
    wcT_kernel<<<768, 256, 0, stream>>>(wc0, wc0T, 1536);
    wcT_kernel<<<1024, 256, 0, stream>>>(wc1, wc1T, 2048);
    cvt_bf16_kernel<<<384, 256, 0, stream>>>(whh, whhb, (1536 * 512) / 8);
    cvt_bf16_kernel<<<512, 256, 0, stream>>>(iw1, wih + (size_t)1024 * 2048, (512 * 2048) / 8);
    bih_kernel<<<6, 256, 0, stream>>>(b1, ib1, bih);
    scan_init_kernel<<<256, 256, 0, stream>>>(hbf, flags);

    // weight GEMMs: w_fh[1024,1536], w_ih[0:1024,2048]
    gemm_nt_kernel<unsigned short, false><<<dim3(8, 12), 256, 0, stream>>>(
        wab0, wc0T, wfh, nullptr, 512, 1536);
    gemm_nt_kernel<unsigned short, false><<<dim3(8, 16), 256, 0, stream>>>(
        wab1, wc1T, wih, nullptr, 512, 2048);

    // big projections: gi[8192,1536], gf[8192,1024]
    gemm_nt_kernel<float, true><<<dim3(64, 12), 256, 0, stream>>>(
        x1bf, wih, gi, bih, 2048, 1536);
    gemm_nt_kernel<float, true><<<dim3(64, 8), 256, 0, stream>>>(
        x0bf, wfh, gf, b0, 1536, 1024);

    // persistent scan: 64 blocks (1 block/CU, all co-resident)
    gru_scan_kernel<<<64, 256, 0, stream>>>(hbf, whhb, bhh, gi, gf, out, hT, flags);
}